// Round 8
// baseline (93.739 us; speedup 1.0000x reference)
//
#include <hip/hip_runtime.h>
#include <stdint.h>
#include <math.h>

typedef __bf16 bf16;
typedef __bf16 bf16x8 __attribute__((ext_vector_type(8)));
typedef __bf16 bf16x4 __attribute__((ext_vector_type(4)));
typedef float f32x4 __attribute__((ext_vector_type(4)));

static constexpr int BATCH = 16384;
static constexpr int D_IN  = 1024;
static constexpr int UNITS = 512;
static constexpr int D_OUT = 512;

__device__ __forceinline__ void gll16(const void* g, void* l) {
    __builtin_amdgcn_global_load_lds(
        (const __attribute__((address_space(1))) void*)g,
        (__attribute__((address_space(3))) void*)l,
        16, 0, 0);
}

// counted vmcnt wait (lgkm/exp = no-wait); N must be < 16
template<int N>
__device__ __forceinline__ void waitvm() {
    static_assert(N < 16, "vmcnt imm");
    __builtin_amdgcn_s_waitcnt(0x0F70 | N);
    asm volatile("" ::: "memory");
}
__device__ __forceinline__ void barrier_raw() {
    asm volatile("" ::: "memory");
    __builtin_amdgcn_s_barrier();
    asm volatile("" ::: "memory");
}

// ---------------- fused weight prep: one launch ----------------
__global__ __launch_bounds__(256)
void k_prep(const float* __restrict__ w_in, const float* __restrict__ sens_w,
            const float* __restrict__ ro_w,
            bf16* __restrict__ w_in_bf, bf16* __restrict__ sensT, bf16* __restrict__ ro_bf)
{
    __shared__ float tile[32][33];
    const int b = blockIdx.x;
    const int t = threadIdx.x;
    if (b < 512) {
        int i = b * 256 + t;
        f32x4 v = ((const f32x4*)w_in)[i];
        bf16x4 o = { (bf16)v.x, (bf16)v.y, (bf16)v.z, (bf16)v.w };
        ((bf16x4*)w_in_bf)[i] = o;
    } else if (b < 768) {
        int bb = b - 512;
        int bx = bb & 15, by = bb >> 4;
        int tx = t & 31, ty = t >> 5;
        #pragma unroll
        for (int j = ty; j < 32; j += 8)
            tile[j][tx] = sens_w[(size_t)(by * 32 + j) * UNITS + bx * 32 + tx];
        __syncthreads();
        #pragma unroll
        for (int j = ty; j < 32; j += 8)
            sensT[(size_t)(bx * 32 + j) * UNITS + by * 32 + tx] = (bf16)tile[tx][j];
    } else {
        int i = (b - 768) * 256 + t;
        f32x4 v = ((const f32x4*)ro_w)[i];
        bf16x4 o = { (bf16)v.x, (bf16)v.y, (bf16)v.z, (bf16)v.w };
        ((bf16x4*)ro_bf)[i] = o;
    }
}

// ======== k_gwide: BM=64, BN=512(full N) — A-strip read ONCE from cache ========
// C[M,512] = epilogue( A[M,K](fp32) @ Bw[512,K]^T + bias ), 512 thr, grid=M/64.
// Rationale: with BN=128 each x-strip was re-read 4x through L3 (268 MB logical,
// L3-BW-bound). Full-N tile cuts logical A traffic to 1x; B (<=1MB bf16) is
// L2-resident. 8 waves = 2m x 4n (wave 32x128, acc 2x8, 16 MFMA/step).
// DEPTH=3 counted-vmcnt ring (T3/T4), rule-21 XOR involutions on both sides.
// EPI 1: out_bf16 = tanh(.)   EPI 3: out_f32 = .
template<int K, int EPI>
__global__ __launch_bounds__(512, 2)
void k_gwide(const float* __restrict__ Af, const bf16* __restrict__ Bw,
             const float* __restrict__ bias,
             float* __restrict__ outF, bf16* __restrict__ outB, int M)
{
    constexpr int N = 512;
    constexpr int NSTEP = K / 32;
    constexpr int DEPTH = 3, L = 5;            // 1 A-gll16 + 4 B-gll16 per thread
    __shared__ __align__(16) char sA[DEPTH][8192];    // 64 rows x 128 B (fp32)
    __shared__ __align__(16) char sB[DEPTH][32768];   // 512 rows x 64 B (bf16)

    const int t = threadIdx.x;
    const int nwg = gridDim.x;
    const int d = blockIdx.x;
    const int bid = (d & 7) * (nwg >> 3) + (d >> 3);  // XCD swizzle (nwg%8==0)
    const int m0 = bid << 6;

    const int lane = t & 63;
    const int wave = t >> 6;            // 2m x 4n
    const int wr = (wave >> 2) * 32;
    const int wc = (wave & 3) * 128;
    const int l15 = lane & 15;
    const int lk  = (lane >> 4) * 8;

    f32x4 acc[2][8];
    #pragma unroll
    for (int m = 0; m < 2; ++m)
        #pragma unroll
        for (int n = 0; n < 8; ++n)
            acc[m][n] = (f32x4){0.f, 0.f, 0.f, 0.f};

    // ---- staging (pre-swizzled source, rule 21) ----
    // A fp32: 64 rows x 8 slots of 16B; slot ^= row&7
    const int ar = t >> 3;
    const int aslot = ((t & 7) ^ (ar & 7)) * 16;
    const char* asrc = (const char*)Af + (size_t)(m0 + ar) * K * 4 + aslot;
    // B bf16: 512 rows x 4 slots of 16B, 128 rows/issue x4; slot ^= (row>>1)&3
    // (+128 rows leaves (row>>1)&3 unchanged -> same per-thread perm each issue)
    const int br = t >> 2;
    const int bslot = ((t & 3) ^ ((br >> 1) & 3)) * 16;
    const char* bsrc = (const char*)Bw + (size_t)br * K * 2 + bslot;

    auto STAGE = [&](int buf, int kt) {
        gll16(asrc + (size_t)kt * 4, &sA[buf][t * 16]);
        const size_t kb = (size_t)kt * 2;
        gll16(bsrc + kb,                        &sB[buf][t * 16]);
        gll16(bsrc + kb + (size_t)128 * K * 2,  &sB[buf][8192  + t * 16]);
        gll16(bsrc + kb + (size_t)256 * K * 2,  &sB[buf][16384 + t * 16]);
        gll16(bsrc + kb + (size_t)384 * K * 2,  &sB[buf][24576 + t * 16]);
    };

    // ---- LDS read offsets (swizzles invariant under +16 rows -> imm steps) ----
    const int Ra = wr + l15;
    const int sa = (Ra & 7) << 4;
    const int aoff0 = Ra * 128 + ((lk * 4) ^ sa);
    const int aoff1 = Ra * 128 + ((lk * 4 + 16) ^ sa);
    const int Rb = wc + l15;
    const int boff = Rb * 64 + ((lk * 2) ^ (((Rb >> 1) & 3) << 4));

    auto COMPUTE = [&](int buf) {
        const char* aB = sA[buf];
        const char* bB = sB[buf];
        bf16x8 afr[2], bfr[8];
        #pragma unroll
        for (int m = 0; m < 2; ++m) {
            f32x4 h0 = *(const f32x4*)(aB + aoff0 + m * 2048);
            f32x4 h1 = *(const f32x4*)(aB + aoff1 + m * 2048);
            afr[m] = (bf16x8){ (bf16)h0.x, (bf16)h0.y, (bf16)h0.z, (bf16)h0.w,
                               (bf16)h1.x, (bf16)h1.y, (bf16)h1.z, (bf16)h1.w };
        }
        #pragma unroll
        for (int n = 0; n < 8; ++n)
            bfr[n] = *(const bf16x8*)(bB + boff + n * 1024);
        #pragma unroll
        for (int m = 0; m < 2; ++m)
            #pragma unroll
            for (int n = 0; n < 8; ++n)
                acc[m][n] = __builtin_amdgcn_mfma_f32_16x16x32_bf16(
                                afr[m], bfr[n], acc[m][n], 0, 0, 0);
    };

    // ---- prologue ----
    #pragma unroll
    for (int p = 0; p < DEPTH; ++p) STAGE(p, p * 32);

    // ---- steady state ----
    int buf = 0;
    int kt_stage = DEPTH * 32;
    for (int i = 0; i < NSTEP - (DEPTH - 1); ++i) {
        waitvm<(DEPTH - 1) * L>();
        barrier_raw();
        COMPUTE(buf);
        barrier_raw();
        if (kt_stage < K) { STAGE(buf, kt_stage); kt_stage += 32; }
        buf = (buf + 1 == DEPTH) ? 0 : buf + 1;
    }
    // ---- tail ----
    waitvm<L>(); barrier_raw(); COMPUTE(buf);
    buf = (buf + 1 == DEPTH) ? 0 : buf + 1;
    waitvm<0>(); barrier_raw(); COMPUTE(buf);
    asm volatile("" ::: "memory");

    // epilogue
    const int rbase = m0 + wr + ((lane >> 4) << 2);
    const int cbase = wc + l15;
    #pragma unroll
    for (int n = 0; n < 8; ++n) {
        const int gc = cbase + n * 16;
        const float bv = bias[gc];
        #pragma unroll
        for (int m = 0; m < 2; ++m) {
            #pragma unroll
            for (int r = 0; r < 4; ++r) {
                const int gr = rbase + m * 16 + r;
                float v = acc[m][n][r] + bv;
                if constexpr (EPI == 1) {
                    float tv = 1.0f - 2.0f / (1.0f + __expf(2.0f * v));
                    outB[(size_t)gr * N + gc] = (bf16)tv;
                } else {
                    outF[(size_t)gr * N + gc] = v;
                }
            }
        }
    }
}

// ======== k_gemm8: R5's proven 128x128 / 8-wave / 3-deep ring (bf16 A) ========
// EPI 2: a=sigmoid(.); out_f32 = a+(states-a)*exp(-0.1/tau)
template<int K, int EPI>
__global__ __launch_bounds__(512, 4)
void k_gemm8(const bf16* __restrict__ Ab, const bf16* __restrict__ Bw,
             const float* __restrict__ bias,
             const float* __restrict__ tau, const float* __restrict__ states,
             float* __restrict__ outF, int M, int N)
{
    constexpr int NSTEP = K / 32;
    constexpr int DEPTH = 3, L = 2;
    __shared__ __align__(16) char sA[DEPTH][8192];
    __shared__ __align__(16) char sB[DEPTH][8192];

    const int t = threadIdx.x;
    const int ntiles = N >> 7;
    const int nwg = gridDim.x;
    const int d = blockIdx.x;
    const int bid = (d & 7) * (nwg >> 3) + (d >> 3);
    const int mtile = bid / ntiles;
    const int ntile = bid % ntiles;
    const int m0 = mtile << 7, n0 = ntile << 7;

    const int lane = t & 63;
    const int wave = t >> 6;            // 4m x 2n, wave 32x64
    const int wr = (wave >> 1) * 32;
    const int wc = (wave & 1) * 64;
    const int l15 = lane & 15;
    const int lk  = (lane >> 4) * 8;

    f32x4 acc[2][4];
    #pragma unroll
    for (int m = 0; m < 2; ++m)
        #pragma unroll
        for (int n = 0; n < 4; ++n)
            acc[m][n] = (f32x4){0.f, 0.f, 0.f, 0.f};

    const int row = t >> 2;
    const int slot = ((t & 3) ^ ((row >> 1) & 3)) * 16;
    const char* asrc = (const char*)Ab + (size_t)(m0 + row) * K * 2 + slot;
    const char* bsrc = (const char*)Bw + (size_t)(n0 + row) * K * 2 + slot;

    auto STAGE = [&](int buf, int kt) {
        const size_t kb = (size_t)kt * 2;
        gll16(asrc + kb, &sA[buf][t * 16]);
        gll16(bsrc + kb, &sB[buf][t * 16]);
    };

    const int Ra = wr + l15;
    const int aoff = Ra * 64 + ((lk * 2) ^ (((Ra >> 1) & 3) << 4));
    const int Rb = wc + l15;
    const int boff = Rb * 64 + ((lk * 2) ^ (((Rb >> 1) & 3) << 4));

    auto COMPUTE = [&](int buf) {
        const char* aB = sA[buf];
        const char* bB = sB[buf];
        bf16x8 afr[2], bfr[4];
        #pragma unroll
        for (int m = 0; m < 2; ++m)
            afr[m] = *(const bf16x8*)(aB + aoff + m * 1024);
        #pragma unroll
        for (int n = 0; n < 4; ++n)
            bfr[n] = *(const bf16x8*)(bB + boff + n * 1024);
        #pragma unroll
        for (int m = 0; m < 2; ++m)
            #pragma unroll
            for (int n = 0; n < 4; ++n)
                acc[m][n] = __builtin_amdgcn_mfma_f32_16x16x32_bf16(
                                afr[m], bfr[n], acc[m][n], 0, 0, 0);
    };

    #pragma unroll
    for (int p = 0; p < DEPTH; ++p) STAGE(p, p * 32);

    int buf = 0;
    int kt_stage = DEPTH * 32;
    for (int i = 0; i < NSTEP - (DEPTH - 1); ++i) {
        waitvm<(DEPTH - 1) * L>();
        barrier_raw();
        COMPUTE(buf);
        barrier_raw();
        if (kt_stage < K) { STAGE(buf, kt_stage); kt_stage += 32; }
        buf = (buf + 1 == DEPTH) ? 0 : buf + 1;
    }
    waitvm<L>(); barrier_raw(); COMPUTE(buf);
    buf = (buf + 1 == DEPTH) ? 0 : buf + 1;
    waitvm<0>(); barrier_raw(); COMPUTE(buf);
    asm volatile("" ::: "memory");

    const int rbase = m0 + wr + ((lane >> 4) << 2);
    const int cbase = n0 + wc + l15;
    #pragma unroll
    for (int n = 0; n < 4; ++n) {
        const int gc = cbase + n * 16;
        const float bv = bias[gc];
        const float dec = __expf(-0.1f / tau[gc]);
        #pragma unroll
        for (int m = 0; m < 2; ++m) {
            #pragma unroll
            for (int r = 0; r < 4; ++r) {
                const int gr = rbase + m * 16 + r;
                float v = acc[m][n][r] + bv;
                float a = 1.0f / (1.0f + __expf(-v));
                float s = states[(size_t)gr * N + gc];
                outF[(size_t)gr * N + gc] = a + (s - a) * dec;
            }
        }
    }
}

extern "C" void kernel_launch(void* const* d_in, const int* in_sizes, int n_in,
                              void* d_out, int out_size, void* d_ws, size_t ws_size,
                              hipStream_t stream) {
    const float* x        = (const float*)d_in[0];
    const float* w_in     = (const float*)d_in[1];
    const float* b_in     = (const float*)d_in[2];
    const float* sens_w   = (const float*)d_in[3];
    const float* sens_sig = (const float*)d_in[4];
    const float* tau      = (const float*)d_in[5];
    const float* ro_w     = (const float*)d_in[6];
    const float* ro_b     = (const float*)d_in[7];
    const float* states   = (const float*)d_in[8];

    float* out    = (float*)d_out;                       // [B][D_OUT] (final, GEMM3)
    float* new_st = out + (size_t)BATCH * D_OUT;         // [B][UNITS] (final, GEMM2)
    bf16*  proj   = (bf16*)d_out;                        // temp bf16 in half1

    bf16* w_in_bf = (bf16*)d_ws;                         // 512*1024
    bf16* sensT   = w_in_bf + (size_t)UNITS * D_IN;      // 512*512 (transposed)
    bf16* ro_bf   = sensT + (size_t)UNITS * UNITS;       // 512*512

    // fused weight prep (single launch)
    k_prep<<<1024, 256, 0, stream>>>(w_in, sens_w, ro_w, w_in_bf, sensT, ro_bf);

    // GEMM1: proj = tanh(x @ w_in^T + b_in) -> bf16; full-N tile, x read once
    k_gwide<1024, 1><<<BATCH / 64, 512, 0, stream>>>(
        x, w_in_bf, b_in, nullptr, proj, BATCH);

    // GEMM2: new_st = sig(proj @ sensT^T + sigma); ODE step -> fp32 (half2, final)
    k_gemm8<512, 2><<<(BATCH / 128) * (UNITS / 128), 512, 0, stream>>>(
        proj, sensT, sens_sig, tau, states, new_st, BATCH, UNITS);

    // GEMM3: out = new_st @ readout^T + ro_b -> fp32 (half1, final); full-N tile
    k_gwide<512, 3><<<BATCH / 64, 512, 0, stream>>>(
        new_st, ro_bf, ro_b, out, nullptr, BATCH);
}

// Round 9
// 88.475 us; speedup vs baseline: 1.0595x; 1.0595x over previous
//
#include <hip/hip_runtime.h>
#include <stdint.h>
#include <math.h>

typedef __bf16 bf16;
typedef __bf16 bf16x8 __attribute__((ext_vector_type(8)));
typedef __bf16 bf16x4 __attribute__((ext_vector_type(4)));
typedef float f32x4 __attribute__((ext_vector_type(4)));

static constexpr int BATCH = 16384;
static constexpr int D_IN  = 1024;
static constexpr int UNITS = 512;
static constexpr int D_OUT = 512;

__device__ __forceinline__ void gll16(const void* g, void* l) {
    __builtin_amdgcn_global_load_lds(
        (const __attribute__((address_space(1))) void*)g,
        (__attribute__((address_space(3))) void*)l,
        16, 0, 0);
}

// counted vmcnt wait (lgkm/exp = no-wait); N must be < 16
template<int N>
__device__ __forceinline__ void waitvm() {
    static_assert(N < 16, "vmcnt imm");
    __builtin_amdgcn_s_waitcnt(0x0F70 | N);
    asm volatile("" ::: "memory");
}
__device__ __forceinline__ void barrier_raw() {
    asm volatile("" ::: "memory");
    __builtin_amdgcn_s_barrier();
    asm volatile("" ::: "memory");
}

// ---------------- streaming cvt: x fp32 -> bf16 (the cold-HBM reader) ----------------
// Barrier-free grid of independent waves streams cold data at ~6 TB/s;
// the lockstep GEMM pipeline measures only ~0.9 TB/s on cold fp32 (R3-R8).
__global__ __launch_bounds__(256) void k_cvt8(const float* __restrict__ in,
                                              bf16* __restrict__ out, int n8) {
    int i = blockIdx.x * blockDim.x + threadIdx.x;
    if (i < n8) {
        f32x4 a = ((const f32x4*)in)[2 * i];
        f32x4 b = ((const f32x4*)in)[2 * i + 1];
        bf16x8 o = { (bf16)a.x, (bf16)a.y, (bf16)a.z, (bf16)a.w,
                     (bf16)b.x, (bf16)b.y, (bf16)b.z, (bf16)b.w };
        ((bf16x8*)out)[i] = o;
    }
}

// ---------------- fused weight prep: one launch ----------------
__global__ __launch_bounds__(256)
void k_prep(const float* __restrict__ w_in, const float* __restrict__ sens_w,
            const float* __restrict__ ro_w,
            bf16* __restrict__ w_in_bf, bf16* __restrict__ sensT, bf16* __restrict__ ro_bf)
{
    __shared__ float tile[32][33];
    const int b = blockIdx.x;
    const int t = threadIdx.x;
    if (b < 512) {
        int i = b * 256 + t;
        f32x4 v = ((const f32x4*)w_in)[i];
        bf16x4 o = { (bf16)v.x, (bf16)v.y, (bf16)v.z, (bf16)v.w };
        ((bf16x4*)w_in_bf)[i] = o;
    } else if (b < 768) {
        int bb = b - 512;
        int bx = bb & 15, by = bb >> 4;
        int tx = t & 31, ty = t >> 5;
        #pragma unroll
        for (int j = ty; j < 32; j += 8)
            tile[j][tx] = sens_w[(size_t)(by * 32 + j) * UNITS + bx * 32 + tx];
        __syncthreads();
        #pragma unroll
        for (int j = ty; j < 32; j += 8)
            sensT[(size_t)(bx * 32 + j) * UNITS + by * 32 + tx] = (bf16)tile[tx][j];
    } else {
        int i = (b - 768) * 256 + t;
        f32x4 v = ((const f32x4*)ro_w)[i];
        bf16x4 o = { (bf16)v.x, (bf16)v.y, (bf16)v.z, (bf16)v.w };
        ((bf16x4*)ro_bf)[i] = o;
    }
}

// ---------------- fused GEMM, 8 waves, 3-deep counted-vmcnt pipeline (R5) ----------------
// C[M,N] = epilogue( A[M,K] @ Bw[N,K]^T + bias ), 128x128 tile, 512 thr.
// LDS ring of 3 tiles; raw s_barrier + counted vmcnt (never 0 in steady state).
// XOR bank-swizzles (rule 21, involution on stage-source AND read):
//   bf16 operands: slot16 ^= (row>>1)&3 ; fp32 A: slot16 ^= row&7
// EPI 1: out_bf16 = tanh(.)  EPI 2: sigmoid + ODE decay  EPI 3: identity
template<int K, int EPI, bool AF32>
__global__ __launch_bounds__(512, 4)
void k_gemm(const float* __restrict__ Af, const bf16* __restrict__ Ab,
            const bf16* __restrict__ Bw,
            const float* __restrict__ bias,
            const float* __restrict__ tau,
            const float* __restrict__ states,
            float* __restrict__ outF, bf16* __restrict__ outB,
            int M, int N)
{
    constexpr int NSTEP = K / 32;
    constexpr int L = AF32 ? 3 : 2;                  // gll16 per thread per stage
    constexpr int ABPB = AF32 ? (128 * 32 * 4) : (128 * 32 * 2);
    __shared__ __align__(16) char sAraw[3][ABPB];
    __shared__ bf16 sB[3][128 * 32];

    const int t = threadIdx.x;
    const int ntiles = N >> 7;
    const int nwg = gridDim.x;
    const int d = blockIdx.x;
    const int bid = (d & 7) * (nwg >> 3) + (d >> 3);  // XCD swizzle (nwg%8==0)
    const int mtile = bid / ntiles;
    const int ntile = bid % ntiles;
    const int m0 = mtile << 7, n0 = ntile << 7;

    const int lane = t & 63;
    const int wave = t >> 6;            // 0..7 -> 4m x 2n sub-tiles of 32x64
    const int wr = (wave >> 1) * 32;
    const int wc = (wave & 1) * 64;
    const int l15 = lane & 15;
    const int lk  = (lane >> 4) * 8;    // k-elem offset of this lane's frag

    f32x4 acc[2][4];
    #pragma unroll
    for (int m = 0; m < 2; ++m)
        #pragma unroll
        for (int n = 0; n < 4; ++n)
            acc[m][n] = (f32x4){0.f, 0.f, 0.f, 0.f};

    // ---- staging source addresses (pre-swizzled global per rule 21) ----
    const int brow = t >> 2;
    const int bslot8 = ((t & 3) ^ ((brow >> 1) & 3)) * 8;      // bf16 elems
    const bf16* bbp = Bw + (size_t)(n0 + brow) * K + bslot8;
    const bf16* abp = AF32 ? nullptr : (Ab + (size_t)(m0 + brow) * K + bslot8);
    const int ar = t >> 3;
    const int aslot16 = ((t & 7) ^ (ar & 7)) * 16;             // bytes
    const char* ag0 = (const char*)Af + (size_t)(m0 + ar) * K * 4 + aslot16;
    const char* ag1 = (const char*)Af + (size_t)(m0 + 64 + ar) * K * 4 + aslot16;

    auto STAGE = [&](int buf, int kt) {
        if constexpr (AF32) {
            gll16(ag0 + (size_t)kt * 4, &sAraw[buf][t * 16]);
            gll16(ag1 + (size_t)kt * 4, &sAraw[buf][8192 + t * 16]);
        } else {
            gll16(abp + kt, &sAraw[buf][t * 16]);
        }
        gll16(bbp + kt, (char*)&sB[buf][0] + t * 16);
    };

    // ---- LDS read offsets (swizzled to match staged layout) ----
    int offB[4];
    #pragma unroll
    for (int n = 0; n < 4; ++n) {
        const int R = wc + n * 16 + l15;
        offB[n] = R * 64 + ((lk * 2) ^ (((R >> 1) & 3) << 4));
    }
    int offA0[2], offA1[2];
    #pragma unroll
    for (int m = 0; m < 2; ++m) {
        const int R = wr + m * 16 + l15;
        if constexpr (AF32) {
            const int s = (R & 7) << 4;
            offA0[m] = R * 128 + ((lk * 4) ^ s);
            offA1[m] = R * 128 + ((lk * 4 + 16) ^ s);
        } else {
            offA0[m] = R * 64 + ((lk * 2) ^ (((R >> 1) & 3) << 4));
        }
    }

    auto COMPUTE = [&](int buf) {
        const char* aB = &sAraw[buf][0];
        const char* bB = (const char*)&sB[buf][0];
        bf16x8 afr[2], bfr[4];
        if constexpr (AF32) {
            #pragma unroll
            for (int m = 0; m < 2; ++m) {
                f32x4 h0 = *(const f32x4*)(aB + offA0[m]);
                f32x4 h1 = *(const f32x4*)(aB + offA1[m]);
                afr[m] = (bf16x8){ (bf16)h0.x, (bf16)h0.y, (bf16)h0.z, (bf16)h0.w,
                                   (bf16)h1.x, (bf16)h1.y, (bf16)h1.z, (bf16)h1.w };
            }
        } else {
            #pragma unroll
            for (int m = 0; m < 2; ++m)
                afr[m] = *(const bf16x8*)(aB + offA0[m]);
        }
        #pragma unroll
        for (int n = 0; n < 4; ++n)
            bfr[n] = *(const bf16x8*)(bB + offB[n]);
        #pragma unroll
        for (int m = 0; m < 2; ++m)
            #pragma unroll
            for (int n = 0; n < 4; ++n)
                acc[m][n] = __builtin_amdgcn_mfma_f32_16x16x32_bf16(
                                afr[m], bfr[n], acc[m][n], 0, 0, 0);
    };

    // ---- prologue: fill the 3-deep ring ----
    STAGE(0, 0);
    STAGE(1, 32);
    STAGE(2, 64);

    // ---- steady state: wait tile i (2L still in flight), compute, restage ----
    int buf = 0;
    int kt_stage = 96;
    for (int i = 0; i < NSTEP - 2; ++i) {
        waitvm<2 * L>();
        barrier_raw();
        COMPUTE(buf);
        barrier_raw();
        if (kt_stage < K) { STAGE(buf, kt_stage); kt_stage += 32; }
        buf = (buf == 2) ? 0 : buf + 1;
    }
    // ---- tail: drain with exact counts ----
    waitvm<L>();
    barrier_raw();
    COMPUTE(buf);
    buf = (buf == 2) ? 0 : buf + 1;
    waitvm<0>();
    barrier_raw();
    COMPUTE(buf);
    asm volatile("" ::: "memory");

    // epilogue: D row = wr + 4*(lane>>4) + r (+16m), col = wc + l15 (+16n)
    const int rbase = m0 + wr + ((lane >> 4) << 2);
    const int cbase = n0 + wc + l15;
    #pragma unroll
    for (int n = 0; n < 4; ++n) {
        const int gc = cbase + n * 16;
        const float bv = bias[gc];
        float dec = 0.f;
        if constexpr (EPI == 2) dec = __expf(-0.1f / tau[gc]);
        #pragma unroll
        for (int m = 0; m < 2; ++m) {
            #pragma unroll
            for (int r = 0; r < 4; ++r) {
                const int gr = rbase + m * 16 + r;
                float v = acc[m][n][r] + bv;
                if constexpr (EPI == 1) {
                    float tv = 1.0f - 2.0f / (1.0f + __expf(2.0f * v));
                    outB[(size_t)gr * N + gc] = (bf16)tv;
                } else if constexpr (EPI == 2) {
                    float a = 1.0f / (1.0f + __expf(-v));
                    float s = states[(size_t)gr * N + gc];
                    outF[(size_t)gr * N + gc] = a + (s - a) * dec;
                } else {
                    outF[(size_t)gr * N + gc] = v;
                }
            }
        }
    }
}

extern "C" void kernel_launch(void* const* d_in, const int* in_sizes, int n_in,
                              void* d_out, int out_size, void* d_ws, size_t ws_size,
                              hipStream_t stream) {
    const float* x        = (const float*)d_in[0];
    const float* w_in     = (const float*)d_in[1];
    const float* b_in     = (const float*)d_in[2];
    const float* sens_w   = (const float*)d_in[3];
    const float* sens_sig = (const float*)d_in[4];
    const float* tau      = (const float*)d_in[5];
    const float* ro_w     = (const float*)d_in[6];
    const float* ro_b     = (const float*)d_in[7];
    const float* states   = (const float*)d_in[8];

    float* out    = (float*)d_out;                       // [B][D_OUT] (final, GEMM3)
    float* new_st = out + (size_t)BATCH * D_OUT;         // [B][UNITS] (final, GEMM2)
    bf16*  proj   = (bf16*)d_out;                        // temp bf16 in half1
    bf16*  x_bf   = (bf16*)new_st;                       // temp bf16 x in half2 (dead until GEMM2 writes)

    bf16* w_in_bf = (bf16*)d_ws;                         // 512*1024
    bf16* sensT   = w_in_bf + (size_t)UNITS * D_IN;      // 512*512 (transposed)
    bf16* ro_bf   = sensT + (size_t)UNITS * UNITS;       // 512*512

    // prep: weights (1 launch) + x -> bf16 (streaming, barrier-free: ~6 TB/s on cold HBM)
    k_prep<<<1024, 256, 0, stream>>>(w_in, sens_w, ro_w, w_in_bf, sensT, ro_bf);
    k_cvt8<<<(BATCH * D_IN / 8 + 255) / 256, 256, 0, stream>>>(x, x_bf, BATCH * D_IN / 8);

    // GEMM1: proj = tanh(x_bf @ w_in^T + b_in) -> bf16 (half1); A is bf16, L3-hot
    k_gemm<1024, 1, false><<<(BATCH / 128) * (UNITS / 128), 512, 0, stream>>>(
        nullptr, x_bf, w_in_bf, b_in, nullptr, nullptr, nullptr, proj, BATCH, UNITS);

    // GEMM2: new_st = sig(proj @ sensT^T + sigma); ODE step -> fp32 (half2, final;
    //        overwrites x_bf which GEMM1 has fully consumed)
    k_gemm<512, 2, false><<<(BATCH / 128) * (UNITS / 128), 512, 0, stream>>>(
        nullptr, proj, sensT, sens_sig, tau, states, new_st, nullptr, BATCH, UNITS);

    // GEMM3: out = new_st @ readout^T + ro_b -> fp32 (half1, final); fp32 A, hot
    k_gemm<512, 3, true><<<(BATCH / 128) * (D_OUT / 128), 512, 0, stream>>>(
        new_st, nullptr, ro_bf, ro_b, nullptr, nullptr, out, nullptr, BATCH, D_OUT);
}

// Round 10
// 88.171 us; speedup vs baseline: 1.0631x; 1.0034x over previous
//
#include <hip/hip_runtime.h>
#include <stdint.h>
#include <math.h>

typedef __bf16 bf16;
typedef __bf16 bf16x8 __attribute__((ext_vector_type(8)));
typedef __bf16 bf16x4 __attribute__((ext_vector_type(4)));
typedef float f32x4 __attribute__((ext_vector_type(4)));

static constexpr int BATCH = 16384;
static constexpr int D_IN  = 1024;
static constexpr int UNITS = 512;
static constexpr int D_OUT = 512;

__device__ __forceinline__ void gll16(const void* g, void* l) {
    __builtin_amdgcn_global_load_lds(
        (const __attribute__((address_space(1))) void*)g,
        (__attribute__((address_space(3))) void*)l,
        16, 0, 0);
}

// counted vmcnt wait (lgkm/exp = no-wait); N must be < 16
template<int N>
__device__ __forceinline__ void waitvm() {
    static_assert(N < 16, "vmcnt imm");
    __builtin_amdgcn_s_waitcnt(0x0F70 | N);
    asm volatile("" ::: "memory");
}
__device__ __forceinline__ void barrier_raw() {
    asm volatile("" ::: "memory");
    __builtin_amdgcn_s_barrier();
    asm volatile("" ::: "memory");
}

// ---------------- streaming cvt: x fp32 -> bf16, XCD-ALIGNED with GEMM1 ----------------
// GEMM1 (grid 512, XCD swizzle) consumes m-strip mt from XCD mt/16. Dispatch
// round-robins blocks: XCD(d)=d&7 [m09]. Remap so XCD x converts exactly the
// strips it will consume: chunk c = (d&7)*1024 + (d>>3) -> XCD x writes rows
// [2048x, 2048x+2048) = strips [16x,16x+16). The converted x_bf then sits
// DIRTY in the consumer's own L2 (4 MB/XCD share) -> GEMM1 stages at L2 rate
// instead of L3 rate (the R1-R9 invariant: hot-A GEMMs are 5x faster).
// Grid MUST be 8192 blocks of 256 (16384*1024 elems / 8 per thread).
__global__ __launch_bounds__(256) void k_cvt8(const float* __restrict__ in,
                                              bf16* __restrict__ out) {
    const int d = blockIdx.x;
    const int c = (d & 7) * 1024 + (d >> 3);       // XCD-aligned chunk id
    const int i = c * 256 + threadIdx.x;           // i8 index (8 elems each)
    f32x4 a = ((const f32x4*)in)[2 * i];
    f32x4 b = ((const f32x4*)in)[2 * i + 1];
    bf16x8 o = { (bf16)a.x, (bf16)a.y, (bf16)a.z, (bf16)a.w,
                 (bf16)b.x, (bf16)b.y, (bf16)b.z, (bf16)b.w };
    ((bf16x8*)out)[i] = o;
}

// ---------------- fused weight prep: one launch ----------------
__global__ __launch_bounds__(256)
void k_prep(const float* __restrict__ w_in, const float* __restrict__ sens_w,
            const float* __restrict__ ro_w,
            bf16* __restrict__ w_in_bf, bf16* __restrict__ sensT, bf16* __restrict__ ro_bf)
{
    __shared__ float tile[32][33];
    const int b = blockIdx.x;
    const int t = threadIdx.x;
    if (b < 512) {
        int i = b * 256 + t;
        f32x4 v = ((const f32x4*)w_in)[i];
        bf16x4 o = { (bf16)v.x, (bf16)v.y, (bf16)v.z, (bf16)v.w };
        ((bf16x4*)w_in_bf)[i] = o;
    } else if (b < 768) {
        int bb = b - 512;
        int bx = bb & 15, by = bb >> 4;
        int tx = t & 31, ty = t >> 5;
        #pragma unroll
        for (int j = ty; j < 32; j += 8)
            tile[j][tx] = sens_w[(size_t)(by * 32 + j) * UNITS + bx * 32 + tx];
        __syncthreads();
        #pragma unroll
        for (int j = ty; j < 32; j += 8)
            sensT[(size_t)(bx * 32 + j) * UNITS + by * 32 + tx] = (bf16)tile[tx][j];
    } else {
        int i = (b - 768) * 256 + t;
        f32x4 v = ((const f32x4*)ro_w)[i];
        bf16x4 o = { (bf16)v.x, (bf16)v.y, (bf16)v.z, (bf16)v.w };
        ((bf16x4*)ro_bf)[i] = o;
    }
}

// ---------------- fused GEMM, 8 waves, 3-deep counted-vmcnt pipeline (R5) ----------------
// C[M,N] = epilogue( A[M,K] @ Bw[N,K]^T + bias ), 128x128 tile, 512 thr.
// LDS ring of 3 tiles; raw s_barrier + counted vmcnt (never 0 in steady state).
// XOR bank-swizzles (rule 21, involution on stage-source AND read):
//   bf16 operands: slot16 ^= (row>>1)&3 ; fp32 A: slot16 ^= row&7
// EPI 1: out_bf16 = tanh(.)  EPI 2: sigmoid + ODE decay  EPI 3: identity
template<int K, int EPI, bool AF32>
__global__ __launch_bounds__(512, 4)
void k_gemm(const float* __restrict__ Af, const bf16* __restrict__ Ab,
            const bf16* __restrict__ Bw,
            const float* __restrict__ bias,
            const float* __restrict__ tau,
            const float* __restrict__ states,
            float* __restrict__ outF, bf16* __restrict__ outB,
            int M, int N)
{
    constexpr int NSTEP = K / 32;
    constexpr int L = AF32 ? 3 : 2;                  // gll16 per thread per stage
    constexpr int ABPB = AF32 ? (128 * 32 * 4) : (128 * 32 * 2);
    __shared__ __align__(16) char sAraw[3][ABPB];
    __shared__ bf16 sB[3][128 * 32];

    const int t = threadIdx.x;
    const int ntiles = N >> 7;
    const int nwg = gridDim.x;
    const int d = blockIdx.x;
    const int bid = (d & 7) * (nwg >> 3) + (d >> 3);  // XCD swizzle (nwg%8==0)
    const int mtile = bid / ntiles;
    const int ntile = bid % ntiles;
    const int m0 = mtile << 7, n0 = ntile << 7;

    const int lane = t & 63;
    const int wave = t >> 6;            // 0..7 -> 4m x 2n sub-tiles of 32x64
    const int wr = (wave >> 1) * 32;
    const int wc = (wave & 1) * 64;
    const int l15 = lane & 15;
    const int lk  = (lane >> 4) * 8;    // k-elem offset of this lane's frag

    f32x4 acc[2][4];
    #pragma unroll
    for (int m = 0; m < 2; ++m)
        #pragma unroll
        for (int n = 0; n < 4; ++n)
            acc[m][n] = (f32x4){0.f, 0.f, 0.f, 0.f};

    // ---- staging source addresses (pre-swizzled global per rule 21) ----
    const int brow = t >> 2;
    const int bslot8 = ((t & 3) ^ ((brow >> 1) & 3)) * 8;      // bf16 elems
    const bf16* bbp = Bw + (size_t)(n0 + brow) * K + bslot8;
    const bf16* abp = AF32 ? nullptr : (Ab + (size_t)(m0 + brow) * K + bslot8);
    const int ar = t >> 3;
    const int aslot16 = ((t & 7) ^ (ar & 7)) * 16;             // bytes
    const char* ag0 = (const char*)Af + (size_t)(m0 + ar) * K * 4 + aslot16;
    const char* ag1 = (const char*)Af + (size_t)(m0 + 64 + ar) * K * 4 + aslot16;

    auto STAGE = [&](int buf, int kt) {
        if constexpr (AF32) {
            gll16(ag0 + (size_t)kt * 4, &sAraw[buf][t * 16]);
            gll16(ag1 + (size_t)kt * 4, &sAraw[buf][8192 + t * 16]);
        } else {
            gll16(abp + kt, &sAraw[buf][t * 16]);
        }
        gll16(bbp + kt, (char*)&sB[buf][0] + t * 16);
    };

    // ---- LDS read offsets (swizzled to match staged layout) ----
    int offB[4];
    #pragma unroll
    for (int n = 0; n < 4; ++n) {
        const int R = wc + n * 16 + l15;
        offB[n] = R * 64 + ((lk * 2) ^ (((R >> 1) & 3) << 4));
    }
    int offA0[2], offA1[2];
    #pragma unroll
    for (int m = 0; m < 2; ++m) {
        const int R = wr + m * 16 + l15;
        if constexpr (AF32) {
            const int s = (R & 7) << 4;
            offA0[m] = R * 128 + ((lk * 4) ^ s);
            offA1[m] = R * 128 + ((lk * 4 + 16) ^ s);
        } else {
            offA0[m] = R * 64 + ((lk * 2) ^ (((R >> 1) & 3) << 4));
        }
    }

    auto COMPUTE = [&](int buf) {
        const char* aB = &sAraw[buf][0];
        const char* bB = (const char*)&sB[buf][0];
        bf16x8 afr[2], bfr[4];
        if constexpr (AF32) {
            #pragma unroll
            for (int m = 0; m < 2; ++m) {
                f32x4 h0 = *(const f32x4*)(aB + offA0[m]);
                f32x4 h1 = *(const f32x4*)(aB + offA1[m]);
                afr[m] = (bf16x8){ (bf16)h0.x, (bf16)h0.y, (bf16)h0.z, (bf16)h0.w,
                                   (bf16)h1.x, (bf16)h1.y, (bf16)h1.z, (bf16)h1.w };
            }
        } else {
            #pragma unroll
            for (int m = 0; m < 2; ++m)
                afr[m] = *(const bf16x8*)(aB + offA0[m]);
        }
        #pragma unroll
        for (int n = 0; n < 4; ++n)
            bfr[n] = *(const bf16x8*)(bB + offB[n]);
        #pragma unroll
        for (int m = 0; m < 2; ++m)
            #pragma unroll
            for (int n = 0; n < 4; ++n)
                acc[m][n] = __builtin_amdgcn_mfma_f32_16x16x32_bf16(
                                afr[m], bfr[n], acc[m][n], 0, 0, 0);
    };

    // ---- prologue: fill the 3-deep ring ----
    STAGE(0, 0);
    STAGE(1, 32);
    STAGE(2, 64);

    // ---- steady state: wait tile i (2L still in flight), compute, restage ----
    int buf = 0;
    int kt_stage = 96;
    for (int i = 0; i < NSTEP - 2; ++i) {
        waitvm<2 * L>();
        barrier_raw();
        COMPUTE(buf);
        barrier_raw();
        if (kt_stage < K) { STAGE(buf, kt_stage); kt_stage += 32; }
        buf = (buf == 2) ? 0 : buf + 1;
    }
    // ---- tail: drain with exact counts ----
    waitvm<L>();
    barrier_raw();
    COMPUTE(buf);
    buf = (buf == 2) ? 0 : buf + 1;
    waitvm<0>();
    barrier_raw();
    COMPUTE(buf);
    asm volatile("" ::: "memory");

    // epilogue: D row = wr + 4*(lane>>4) + r (+16m), col = wc + l15 (+16n)
    const int rbase = m0 + wr + ((lane >> 4) << 2);
    const int cbase = n0 + wc + l15;
    #pragma unroll
    for (int n = 0; n < 4; ++n) {
        const int gc = cbase + n * 16;
        const float bv = bias[gc];
        float dec = 0.f;
        if constexpr (EPI == 2) dec = __expf(-0.1f / tau[gc]);
        #pragma unroll
        for (int m = 0; m < 2; ++m) {
            #pragma unroll
            for (int r = 0; r < 4; ++r) {
                const int gr = rbase + m * 16 + r;
                float v = acc[m][n][r] + bv;
                if constexpr (EPI == 1) {
                    float tv = 1.0f - 2.0f / (1.0f + __expf(2.0f * v));
                    outB[(size_t)gr * N + gc] = (bf16)tv;
                } else if constexpr (EPI == 2) {
                    float a = 1.0f / (1.0f + __expf(-v));
                    float s = states[(size_t)gr * N + gc];
                    outF[(size_t)gr * N + gc] = a + (s - a) * dec;
                } else {
                    outF[(size_t)gr * N + gc] = v;
                }
            }
        }
    }
}

extern "C" void kernel_launch(void* const* d_in, const int* in_sizes, int n_in,
                              void* d_out, int out_size, void* d_ws, size_t ws_size,
                              hipStream_t stream) {
    const float* x        = (const float*)d_in[0];
    const float* w_in     = (const float*)d_in[1];
    const float* b_in     = (const float*)d_in[2];
    const float* sens_w   = (const float*)d_in[3];
    const float* sens_sig = (const float*)d_in[4];
    const float* tau      = (const float*)d_in[5];
    const float* ro_w     = (const float*)d_in[6];
    const float* ro_b     = (const float*)d_in[7];
    const float* states   = (const float*)d_in[8];

    float* out    = (float*)d_out;                       // [B][D_OUT] (final, GEMM3)
    float* new_st = out + (size_t)BATCH * D_OUT;         // [B][UNITS] (final, GEMM2)
    bf16*  proj   = (bf16*)d_out;                        // temp bf16 in half1
    bf16*  x_bf   = (bf16*)new_st;                       // temp bf16 x in half2 (dead until GEMM2 writes)

    bf16* w_in_bf = (bf16*)d_ws;                         // 512*1024
    bf16* sensT   = w_in_bf + (size_t)UNITS * D_IN;      // 512*512 (transposed)
    bf16* ro_bf   = sensT + (size_t)UNITS * UNITS;       // 512*512

    // prep: weights (1 launch) + x -> bf16 XCD-aligned with GEMM1's consumer mapping
    k_prep<<<1024, 256, 0, stream>>>(w_in, sens_w, ro_w, w_in_bf, sensT, ro_bf);
    k_cvt8<<<BATCH * D_IN / 8 / 256, 256, 0, stream>>>(x, x_bf);   // 8192 blocks exactly

    // GEMM1: proj = tanh(x_bf @ w_in^T + b_in) -> bf16 (half1); A now same-XCD-L2-hot
    k_gemm<1024, 1, false><<<(BATCH / 128) * (UNITS / 128), 512, 0, stream>>>(
        nullptr, x_bf, w_in_bf, b_in, nullptr, nullptr, nullptr, proj, BATCH, UNITS);

    // GEMM2: new_st = sig(proj @ sensT^T + sigma); ODE step -> fp32 (half2, final;
    //        overwrites x_bf which GEMM1 has fully consumed)
    k_gemm<512, 2, false><<<(BATCH / 128) * (UNITS / 128), 512, 0, stream>>>(
        nullptr, proj, sensT, sens_sig, tau, states, new_st, nullptr, BATCH, UNITS);

    // GEMM3: out = new_st @ readout^T + ro_b -> fp32 (half1, final); fp32 A, hot
    k_gemm<512, 3, true><<<(BATCH / 128) * (D_OUT / 128), 512, 0, stream>>>(
        new_st, nullptr, ro_bf, ro_b, nullptr, nullptr, out, nullptr, BATCH, D_OUT);
}

// Round 11
// 85.541 us; speedup vs baseline: 1.0958x; 1.0307x over previous
//
#include <hip/hip_runtime.h>
#include <stdint.h>
#include <math.h>

typedef __bf16 bf16;
typedef __bf16 bf16x8 __attribute__((ext_vector_type(8)));
typedef __bf16 bf16x4 __attribute__((ext_vector_type(4)));
typedef float f32x4 __attribute__((ext_vector_type(4)));

static constexpr int BATCH = 16384;
static constexpr int D_IN  = 1024;
static constexpr int UNITS = 512;
static constexpr int D_OUT = 512;

__device__ __forceinline__ void gll16(const void* g, void* l) {
    __builtin_amdgcn_global_load_lds(
        (const __attribute__((address_space(1))) void*)g,
        (__attribute__((address_space(3))) void*)l,
        16, 0, 0);
}

template<int N>
__device__ __forceinline__ void waitvm() {
    static_assert(N < 16, "vmcnt imm");
    __builtin_amdgcn_s_waitcnt(0x0F70 | N);
    asm volatile("" ::: "memory");
}
__device__ __forceinline__ void barrier_raw() {
    asm volatile("" ::: "memory");
    __builtin_amdgcn_s_barrier();
    asm volatile("" ::: "memory");
}

// ---------------- k_pack: x -> bf16 PRE-PACKED in GEMM1's staged-tile order,
//                  fused with weight prep (one launch) ----------------
// xp[strip s][kstep j] is an 8 KB chunk whose byte t*16 equals exactly what
// GEMM1's thread t DMAs for (mtile=s, kt=32j) — including the bank-swizzle
// permutation slot8 = ((t&3)^((t>>3)&3))*8. GEMM1's A-stage then reads ONE
// CONTIGUOUS 8 KB per step: full 128B-line utilization at L3 (the old
// row-major layout read 64 B per 2 KB row -> 2x line-granule waste, and the
// 4x n-tile re-read multiplied it; that tax matched G1's entire deficit).
// blocks [0,4096): pack (b -> strip b>>5, kstep b&31; 2 slots/thread)
// blocks [4096,4608): w_in cvt   [4608,4864): sensT transpose  [4864,5120): ro cvt
__global__ __launch_bounds__(256)
void k_pack(const float* __restrict__ x, char* __restrict__ xp,
            const float* __restrict__ w_in, const float* __restrict__ sens_w,
            const float* __restrict__ ro_w,
            bf16* __restrict__ w_in_bf, bf16* __restrict__ sensT, bf16* __restrict__ ro_bf)
{
    __shared__ float tile[32][33];
    const int b = blockIdx.x;
    const int t = threadIdx.x;
    if (b < 4096) {
        const int mt = b >> 5, j = b & 31;
        #pragma unroll
        for (int h = 0; h < 2; ++h) {
            const int v = t + h * 256;
            const int row = mt * 128 + (v >> 2);
            const int kb = j * 32 + ((v & 3) ^ ((v >> 3) & 3)) * 8;
            const float* src = x + (size_t)row * D_IN + kb;
            f32x4 a = ((const f32x4*)src)[0];
            f32x4 c = ((const f32x4*)src)[1];
            bf16x8 o = { (bf16)a.x, (bf16)a.y, (bf16)a.z, (bf16)a.w,
                         (bf16)c.x, (bf16)c.y, (bf16)c.z, (bf16)c.w };
            *(bf16x8*)(xp + (size_t)b * 8192 + (size_t)v * 16) = o;
        }
    } else if (b < 4608) {
        int i = (b - 4096) * 256 + t;
        f32x4 v = ((const f32x4*)w_in)[i];
        bf16x4 o = { (bf16)v.x, (bf16)v.y, (bf16)v.z, (bf16)v.w };
        ((bf16x4*)w_in_bf)[i] = o;
    } else if (b < 4864) {
        int bb = b - 4608;
        int bx = bb & 15, by = bb >> 4;
        int tx = t & 31, ty = t >> 5;
        #pragma unroll
        for (int j = ty; j < 32; j += 8)
            tile[j][tx] = sens_w[(size_t)(by * 32 + j) * UNITS + bx * 32 + tx];
        __syncthreads();
        #pragma unroll
        for (int j = ty; j < 32; j += 8)
            sensT[(size_t)(bx * 32 + j) * UNITS + by * 32 + tx] = (bf16)tile[tx][j];
    } else {
        int i = (b - 4864) * 256 + t;
        f32x4 v = ((const f32x4*)ro_w)[i];
        bf16x4 o = { (bf16)v.x, (bf16)v.y, (bf16)v.z, (bf16)v.w };
        ((bf16x4*)ro_bf)[i] = o;
    }
}

// ---------------- fused GEMM, 8 waves, 3-deep counted-vmcnt pipeline ----------------
// C[M,N] = epilogue( A[M,K] @ Bw[N,K]^T + bias ), 128x128 tile, 512 thr.
// APACK: A staged from pre-packed chunks (one contiguous 8 KB gll16 sweep/step).
// XOR bank-swizzles (rule 21): bf16 slot16 ^= (row>>1)&3 ; fp32 A slot16 ^= row&7.
// EPI 1: out_bf16 = tanh(.)  EPI 2: sigmoid + ODE decay  EPI 3: identity
template<int K, int EPI, bool AF32, bool APACK>
__global__ __launch_bounds__(512, 4)
void k_gemm(const float* __restrict__ Af, const bf16* __restrict__ Ab,
            const bf16* __restrict__ Bw,
            const float* __restrict__ bias,
            const float* __restrict__ tau,
            const float* __restrict__ states,
            float* __restrict__ outF, bf16* __restrict__ outB,
            int M, int N)
{
    constexpr int NSTEP = K / 32;
    constexpr int L = AF32 ? 3 : 2;                  // gll16 per thread per stage
    constexpr int ABPB = AF32 ? (128 * 32 * 4) : (128 * 32 * 2);
    __shared__ __align__(16) char sAraw[3][ABPB];
    __shared__ bf16 sB[3][128 * 32];

    const int t = threadIdx.x;
    const int ntiles = N >> 7;
    const int nwg = gridDim.x;
    const int d = blockIdx.x;
    const int bid = (d & 7) * (nwg >> 3) + (d >> 3);  // XCD swizzle (nwg%8==0)
    const int mtile = bid / ntiles;
    const int ntile = bid % ntiles;
    const int m0 = mtile << 7, n0 = ntile << 7;

    const int lane = t & 63;
    const int wave = t >> 6;            // 0..7 -> 4m x 2n sub-tiles of 32x64
    const int wr = (wave >> 1) * 32;
    const int wc = (wave & 1) * 64;
    const int l15 = lane & 15;
    const int lk  = (lane >> 4) * 8;

    f32x4 acc[2][4];
    #pragma unroll
    for (int m = 0; m < 2; ++m)
        #pragma unroll
        for (int n = 0; n < 4; ++n)
            acc[m][n] = (f32x4){0.f, 0.f, 0.f, 0.f};

    // ---- staging source addresses ----
    const int brow = t >> 2;
    const int bslot8 = ((t & 3) ^ ((brow >> 1) & 3)) * 8;
    const bf16* bbp = Bw + (size_t)(n0 + brow) * K + bslot8;
    const bf16* abp = (AF32 || APACK) ? nullptr : (Ab + (size_t)(m0 + brow) * K + bslot8);
    const char* apk = APACK ? ((const char*)Ab + (size_t)mtile * NSTEP * 8192 + (size_t)t * 16)
                            : nullptr;
    const int ar = t >> 3;
    const int aslot16 = ((t & 7) ^ (ar & 7)) * 16;
    const char* ag0 = (const char*)Af + (size_t)(m0 + ar) * K * 4 + aslot16;
    const char* ag1 = (const char*)Af + (size_t)(m0 + 64 + ar) * K * 4 + aslot16;

    auto STAGE = [&](int buf, int kt) {
        if constexpr (AF32) {
            gll16(ag0 + (size_t)kt * 4, &sAraw[buf][t * 16]);
            gll16(ag1 + (size_t)kt * 4, &sAraw[buf][8192 + t * 16]);
        } else if constexpr (APACK) {
            gll16(apk + (size_t)kt * 256, &sAraw[buf][t * 16]);   // (kt/32)*8192
        } else {
            gll16(abp + kt, &sAraw[buf][t * 16]);
        }
        gll16(bbp + kt, (char*)&sB[buf][0] + t * 16);
    };

    // ---- LDS read offsets (swizzled; identical LDS image for all A paths) ----
    int offB[4];
    #pragma unroll
    for (int n = 0; n < 4; ++n) {
        const int R = wc + n * 16 + l15;
        offB[n] = R * 64 + ((lk * 2) ^ (((R >> 1) & 3) << 4));
    }
    int offA0[2], offA1[2];
    #pragma unroll
    for (int m = 0; m < 2; ++m) {
        const int R = wr + m * 16 + l15;
        if constexpr (AF32) {
            const int s = (R & 7) << 4;
            offA0[m] = R * 128 + ((lk * 4) ^ s);
            offA1[m] = R * 128 + ((lk * 4 + 16) ^ s);
        } else {
            offA0[m] = R * 64 + ((lk * 2) ^ (((R >> 1) & 3) << 4));
        }
    }

    auto COMPUTE = [&](int buf) {
        const char* aB = &sAraw[buf][0];
        const char* bB = (const char*)&sB[buf][0];
        bf16x8 afr[2], bfr[4];
        if constexpr (AF32) {
            #pragma unroll
            for (int m = 0; m < 2; ++m) {
                f32x4 h0 = *(const f32x4*)(aB + offA0[m]);
                f32x4 h1 = *(const f32x4*)(aB + offA1[m]);
                afr[m] = (bf16x8){ (bf16)h0.x, (bf16)h0.y, (bf16)h0.z, (bf16)h0.w,
                                   (bf16)h1.x, (bf16)h1.y, (bf16)h1.z, (bf16)h1.w };
            }
        } else {
            #pragma unroll
            for (int m = 0; m < 2; ++m)
                afr[m] = *(const bf16x8*)(aB + offA0[m]);
        }
        #pragma unroll
        for (int n = 0; n < 4; ++n)
            bfr[n] = *(const bf16x8*)(bB + offB[n]);
        #pragma unroll
        for (int m = 0; m < 2; ++m)
            #pragma unroll
            for (int n = 0; n < 4; ++n)
                acc[m][n] = __builtin_amdgcn_mfma_f32_16x16x32_bf16(
                                afr[m], bfr[n], acc[m][n], 0, 0, 0);
    };

    // ---- prologue: fill the 3-deep ring ----
    STAGE(0, 0);
    STAGE(1, 32);
    STAGE(2, 64);

    // ---- steady state: wait tile i (2L still in flight), compute, restage ----
    int buf = 0;
    int kt_stage = 96;
    for (int i = 0; i < NSTEP - 2; ++i) {
        waitvm<2 * L>();
        barrier_raw();
        COMPUTE(buf);
        barrier_raw();
        if (kt_stage < K) { STAGE(buf, kt_stage); kt_stage += 32; }
        buf = (buf == 2) ? 0 : buf + 1;
    }
    // ---- tail ----
    waitvm<L>();
    barrier_raw();
    COMPUTE(buf);
    buf = (buf == 2) ? 0 : buf + 1;
    waitvm<0>();
    barrier_raw();
    COMPUTE(buf);
    asm volatile("" ::: "memory");

    // epilogue
    const int rbase = m0 + wr + ((lane >> 4) << 2);
    const int cbase = n0 + wc + l15;
    #pragma unroll
    for (int n = 0; n < 4; ++n) {
        const int gc = cbase + n * 16;
        const float bv = bias[gc];
        float dec = 0.f;
        if constexpr (EPI == 2) dec = __expf(-0.1f / tau[gc]);
        #pragma unroll
        for (int m = 0; m < 2; ++m) {
            #pragma unroll
            for (int r = 0; r < 4; ++r) {
                const int gr = rbase + m * 16 + r;
                float v = acc[m][n][r] + bv;
                if constexpr (EPI == 1) {
                    float tv = 1.0f - 2.0f / (1.0f + __expf(2.0f * v));
                    outB[(size_t)gr * N + gc] = (bf16)tv;
                } else if constexpr (EPI == 2) {
                    float a = 1.0f / (1.0f + __expf(-v));
                    float s = states[(size_t)gr * N + gc];
                    outF[(size_t)gr * N + gc] = a + (s - a) * dec;
                } else {
                    outF[(size_t)gr * N + gc] = v;
                }
            }
        }
    }
}

extern "C" void kernel_launch(void* const* d_in, const int* in_sizes, int n_in,
                              void* d_out, int out_size, void* d_ws, size_t ws_size,
                              hipStream_t stream) {
    const float* x        = (const float*)d_in[0];
    const float* w_in     = (const float*)d_in[1];
    const float* b_in     = (const float*)d_in[2];
    const float* sens_w   = (const float*)d_in[3];
    const float* sens_sig = (const float*)d_in[4];
    const float* tau      = (const float*)d_in[5];
    const float* ro_w     = (const float*)d_in[6];
    const float* ro_b     = (const float*)d_in[7];
    const float* states   = (const float*)d_in[8];

    float* out    = (float*)d_out;                       // [B][D_OUT] (final, GEMM3)
    float* new_st = out + (size_t)BATCH * D_OUT;         // [B][UNITS] (final, GEMM2)
    bf16*  proj   = (bf16*)d_out;                        // temp bf16 in half1
    char*  xp     = (char*)new_st;                       // packed x_bf, 33,554,432 B exact fit
                                                         // (dead until GEMM2 writes new_st)
    bf16* w_in_bf = (bf16*)d_ws;                         // 512*1024
    bf16* sensT   = w_in_bf + (size_t)UNITS * D_IN;      // 512*512 (transposed)
    bf16* ro_bf   = sensT + (size_t)UNITS * UNITS;       // 512*512

    // pack x (staged-tile layout) + weight prep, one launch
    k_pack<<<5120, 256, 0, stream>>>(x, xp, w_in, sens_w, ro_w, w_in_bf, sensT, ro_bf);

    // GEMM1: proj = tanh(x @ w_in^T + b_in) -> bf16 (half1); A from packed chunks
    k_gemm<1024, 1, false, true><<<(BATCH / 128) * (UNITS / 128), 512, 0, stream>>>(
        nullptr, (const bf16*)xp, w_in_bf, b_in, nullptr, nullptr, nullptr, proj, BATCH, UNITS);

    // GEMM2: new_st = sig(proj @ sensT^T + sigma); ODE step -> fp32 (half2, final;
    //        overwrites xp which GEMM1 has fully consumed)
    k_gemm<512, 2, false, false><<<(BATCH / 128) * (UNITS / 128), 512, 0, stream>>>(
        nullptr, proj, sensT, sens_sig, tau, states, new_st, nullptr, BATCH, UNITS);

    // GEMM3: out = new_st @ readout^T + ro_b -> fp32 (half1, final); fp32 A, hot
    k_gemm<512, 3, true, false><<<(BATCH / 128) * (D_OUT / 128), 512, 0, stream>>>(
        new_st, nullptr, ro_bf, ro_b, nullptr, nullptr, out, nullptr, BATCH, D_OUT);
}